// Round 1
// baseline (1124.334 us; speedup 1.0000x reference)
//
#include <hip/hip_runtime.h>
#include <hip/hip_bf16.h>

#define NN 100000
#define NE 1200000
#define NG 512

// ---------------- CSR build ----------------
__global__ void k_init_cnt(int* cnt, int n) {
    int i = blockIdx.x * blockDim.x + threadIdx.x;
    if (i < n) cnt[i] = 1;  // self-loop contributes 1 per node
}

__global__ void k_hist(const int* __restrict__ dst, int e, int* cnt) {
    int i = blockIdx.x * blockDim.x + threadIdx.x;
    if (i < e) atomicAdd(&cnt[dst[i]], 1);
}

__global__ void k_scan1(const int* __restrict__ cnt, int n, int* ex, int* blkSum) {
    __shared__ int s[1024];
    int i = blockIdx.x * 1024 + threadIdx.x;
    int v = (i < n) ? cnt[i] : 0;
    s[threadIdx.x] = v;
    __syncthreads();
    for (int off = 1; off < 1024; off <<= 1) {
        int t = (threadIdx.x >= off) ? s[threadIdx.x - off] : 0;
        __syncthreads();
        s[threadIdx.x] += t;
        __syncthreads();
    }
    if (i < n) ex[i] = s[threadIdx.x] - v;   // exclusive within block
    if (threadIdx.x == 1023) blkSum[blockIdx.x] = s[1023];
}

__global__ void k_scan2(const int* __restrict__ blkSum, int nb, int* blkOff, int* totalOut) {
    __shared__ int s[128];
    int t = threadIdx.x;
    int v = (t < nb) ? blkSum[t] : 0;
    s[t] = v;
    __syncthreads();
    for (int off = 1; off < 128; off <<= 1) {
        int x = (t >= off) ? s[t - off] : 0;
        __syncthreads();
        s[t] += x;
        __syncthreads();
    }
    if (t < nb) blkOff[t] = s[t] - v;
    if (t == 127) *totalOut = s[127];  // row_ptr[N] = total edge count
}

__global__ void k_scan3(int* row_ptr, int* cursor, const int* __restrict__ blkOff, int n) {
    int i = blockIdx.x * blockDim.x + threadIdx.x;
    if (i < n) {
        int v = row_ptr[i] + blkOff[i >> 10];
        row_ptr[i] = v;
        cursor[i] = v;
    }
}

__global__ void k_scatter(const int* __restrict__ srcA, const int* __restrict__ dstA,
                          int e, int n, int* cursor, int* __restrict__ col) {
    int i = blockIdx.x * blockDim.x + threadIdx.x;
    if (i < e) {
        int d = dstA[i];
        int pos = atomicAdd(&cursor[d], 1);
        col[pos] = srcA[i];
    } else if (i < e + n) {
        int v = i - e;  // self loop
        int pos = atomicAdd(&cursor[v], 1);
        col[pos] = v;
    }
}

// ---------------- GEMM + attention scores ----------------
// h = X @ W  (X:[n,K], W:[K,64]), s_src = h . a_src, s_dst = h . a_dst
// block = 256 thr = 4 waves; each wave computes 4 rows; lane = output feature.
template <int K>
__global__ __launch_bounds__(256) void k_gemm_att(
    const float* __restrict__ X, const float* __restrict__ W,
    const float* __restrict__ a_src, const float* __restrict__ a_dst,
    float* __restrict__ H, float* __restrict__ ssrc, float* __restrict__ sdst, int n) {
    __shared__ float Wl[K * 64];
    for (int idx = threadIdx.x; idx < K * 64; idx += 256) Wl[idx] = W[idx];
    __syncthreads();
    const int wave = threadIdx.x >> 6, lane = threadIdx.x & 63;
    const float as = a_src[lane], ad = a_dst[lane];
    const int base = (blockIdx.x * 4 + wave) * 4;
    if (base >= n) return;
    float acc0 = 0.f, acc1 = 0.f, acc2 = 0.f, acc3 = 0.f;
    const float* x0 = X + (size_t)(base + 0) * K;
    const float* x1 = X + (size_t)(base + 1) * K;
    const float* x2 = X + (size_t)(base + 2) * K;
    const float* x3 = X + (size_t)(base + 3) * K;
    for (int k = 0; k < K; k += 4) {
        float4 a = *reinterpret_cast<const float4*>(x0 + k);
        float4 b = *reinterpret_cast<const float4*>(x1 + k);
        float4 c = *reinterpret_cast<const float4*>(x2 + k);
        float4 d = *reinterpret_cast<const float4*>(x3 + k);
        const float* ap = reinterpret_cast<const float*>(&a);
        const float* bp = reinterpret_cast<const float*>(&b);
        const float* cp = reinterpret_cast<const float*>(&c);
        const float* dp = reinterpret_cast<const float*>(&d);
#pragma unroll
        for (int j = 0; j < 4; ++j) {
            float w = Wl[(k + j) * 64 + lane];
            acc0 += ap[j] * w;
            acc1 += bp[j] * w;
            acc2 += cp[j] * w;
            acc3 += dp[j] * w;
        }
    }
    float accs[4] = {acc0, acc1, acc2, acc3};
#pragma unroll
    for (int r = 0; r < 4; ++r) {
        H[(size_t)(base + r) * 64 + lane] = accs[r];
        float ds = accs[r] * as, dd = accs[r] * ad;
#pragma unroll
        for (int off = 32; off; off >>= 1) {
            ds += __shfl_xor(ds, off);
            dd += __shfl_xor(dd, off);
        }
        if (lane == 0) {
            ssrc[base + r] = ds;
            sdst[base + r] = dd;
        }
    }
}

// ---------------- GAT aggregation (online softmax) ----------------
// one wave per dst node; lane = feature
__global__ __launch_bounds__(256) void k_agg(
    const float* __restrict__ H, const float* __restrict__ ssrc,
    const float* __restrict__ sdst, const int* __restrict__ row_ptr,
    const int* __restrict__ col, const float* __restrict__ bias,
    float* __restrict__ Y, int n) {
    int dst = blockIdx.x * 4 + (threadIdx.x >> 6);
    int lane = threadIdx.x & 63;
    if (dst >= n) return;
    int beg = row_ptr[dst], end = row_ptr[dst + 1];
    float sd = sdst[dst];
    float m = -INFINITY, denom = 0.f, acc = 0.f;
    for (int j = beg; j < end; ++j) {
        int src = col[j];
        float e = ssrc[src] + sd;
        e = (e > 0.f) ? e : 0.2f * e;  // LeakyReLU
        float hv = H[(size_t)src * 64 + lane];
        if (e > m) {                    // wave-uniform branch (e lane-invariant)
            float c = __expf(m - e);    // first iter: exp(-inf)=0
            denom = denom * c + 1.f;
            acc = acc * c + hv;
            m = e;
        } else {
            float w = __expf(e - m);
            denom += w;
            acc += w * hv;
        }
    }
    float o = acc / denom + bias[lane];
    Y[(size_t)dst * 64 + lane] = (o > 0.f) ? o : 0.f;
}

// ---------------- pooling boundaries + pool + FC ----------------
__global__ void k_gstart(const int* __restrict__ batch, int n, int* gs) {
    int g = blockIdx.x * blockDim.x + threadIdx.x;
    if (g > NG) return;
    int lo = 0, hi = n;
    while (lo < hi) {
        int mid = (lo + hi) >> 1;
        if (batch[mid] < g) lo = mid + 1; else hi = mid;
    }
    gs[g] = lo;
}

__global__ __launch_bounds__(64) void k_pool_fc(
    const float* __restrict__ Y, const int* __restrict__ gs,
    const float* __restrict__ fcW, const float* __restrict__ fcb,
    float* __restrict__ out) {
    __shared__ float p[64];
    int g = blockIdx.x, lane = threadIdx.x;
    int b = gs[g], e = gs[g + 1];
    float s = 0.f;
    for (int r = b; r < e; ++r) s += Y[(size_t)r * 64 + lane];
    int cnt = e - b;
    p[lane] = s / (float)(cnt > 0 ? cnt : 1);
    __syncthreads();
    if (lane < 32) {
        float acc = fcb[lane];
#pragma unroll
        for (int k = 0; k < 64; ++k) acc += p[k] * fcW[k * 32 + lane];
        out[g * 32 + lane] = acc;
    }
}

// ---------------- launch ----------------
extern "C" void kernel_launch(void* const* d_in, const int* in_sizes, int n_in,
                              void* d_out, int out_size, void* d_ws, size_t ws_size,
                              hipStream_t stream) {
    const float* x = (const float*)d_in[0];
    const int* ei = (const int*)d_in[1];
    const int* batch = (const int*)d_in[2];
    const float* W0 = (const float*)d_in[3];
    const float* as0 = (const float*)d_in[4];
    const float* ad0 = (const float*)d_in[5];
    const float* b0 = (const float*)d_in[6];
    const float* W1 = (const float*)d_in[7];
    const float* as1 = (const float*)d_in[8];
    const float* ad1 = (const float*)d_in[9];
    const float* b1 = (const float*)d_in[10];
    const float* W2 = (const float*)d_in[11];
    const float* as2 = (const float*)d_in[12];
    const float* ad2 = (const float*)d_in[13];
    const float* b2 = (const float*)d_in[14];
    const float* fcW = (const float*)d_in[15];
    const float* fcb = (const float*)d_in[16];
    float* out = (float*)d_out;

    char* w = (char*)d_ws;
    auto alloc = [&](size_t bytes) {
        void* p = (void*)w;
        w += (bytes + 255) & ~(size_t)255;
        return p;
    };
    int* cnt_cursor = (int*)alloc((size_t)NN * 4);       // counts, then cursor
    int* row_ptr = (int*)alloc((size_t)(NN + 1) * 4);
    int* blkSum = (int*)alloc(512);
    int* blkOff = (int*)alloc(512);
    int* col = (int*)alloc((size_t)(NE + NN) * 4);
    int* gs = (int*)alloc((size_t)(NG + 1) * 4);
    float* H = (float*)alloc((size_t)NN * 64 * 4);
    float* Y = (float*)alloc((size_t)NN * 64 * 4);
    float* ssrc = (float*)alloc((size_t)NN * 4);
    float* sdst = (float*)alloc((size_t)NN * 4);

    const int* srcA = ei;
    const int* dstA = ei + NE;

    // CSR build
    k_init_cnt<<<(NN + 255) / 256, 256, 0, stream>>>(cnt_cursor, NN);
    k_hist<<<(NE + 255) / 256, 256, 0, stream>>>(dstA, NE, cnt_cursor);
    const int nb = (NN + 1023) / 1024;  // 98
    k_scan1<<<nb, 1024, 0, stream>>>(cnt_cursor, NN, row_ptr, blkSum);
    k_scan2<<<1, 128, 0, stream>>>(blkSum, nb, blkOff, row_ptr + NN);
    k_scan3<<<(NN + 255) / 256, 256, 0, stream>>>(row_ptr, cnt_cursor, blkOff, NN);
    k_scatter<<<(NE + NN + 255) / 256, 256, 0, stream>>>(srcA, dstA, NE, NN, cnt_cursor, col);
    k_gstart<<<3, 256, 0, stream>>>(batch, NN, gs);

    const int gemm_grid = (NN + 15) / 16;   // 4 waves * 4 rows per block
    const int agg_grid = (NN + 3) / 4;      // 4 waves per block, wave per dst

    // layer 0
    k_gemm_att<128><<<gemm_grid, 256, 0, stream>>>(x, W0, as0, ad0, H, ssrc, sdst, NN);
    k_agg<<<agg_grid, 256, 0, stream>>>(H, ssrc, sdst, row_ptr, col, b0, Y, NN);
    // layer 1
    k_gemm_att<64><<<gemm_grid, 256, 0, stream>>>(Y, W1, as1, ad1, H, ssrc, sdst, NN);
    k_agg<<<agg_grid, 256, 0, stream>>>(H, ssrc, sdst, row_ptr, col, b1, Y, NN);
    // layer 2
    k_gemm_att<64><<<gemm_grid, 256, 0, stream>>>(Y, W2, as2, ad2, H, ssrc, sdst, NN);
    k_agg<<<agg_grid, 256, 0, stream>>>(H, ssrc, sdst, row_ptr, col, b2, Y, NN);

    // pool + FC
    k_pool_fc<<<NG, 64, 0, stream>>>(Y, gs, fcW, fcb, out);
}

// Round 2
// 731.377 us; speedup vs baseline: 1.5373x; 1.5373x over previous
//
#include <hip/hip_runtime.h>
#include <hip/hip_bf16.h>

#define NN 100000
#define NE 1200000
#define NG 512

// ---------------- CSR build ----------------
__global__ void k_init_cnt(int* cnt, int n) {
    int i = blockIdx.x * blockDim.x + threadIdx.x;
    if (i < n) cnt[i] = 1;  // self-loop contributes 1 per node
}

__global__ void k_hist(const int* __restrict__ dst, int e, int* cnt) {
    int i = blockIdx.x * blockDim.x + threadIdx.x;
    if (i < e) atomicAdd(&cnt[dst[i]], 1);
}

__global__ void k_scan1(const int* __restrict__ cnt, int n, int* ex, int* blkSum) {
    __shared__ int s[1024];
    int i = blockIdx.x * 1024 + threadIdx.x;
    int v = (i < n) ? cnt[i] : 0;
    s[threadIdx.x] = v;
    __syncthreads();
    for (int off = 1; off < 1024; off <<= 1) {
        int t = (threadIdx.x >= off) ? s[threadIdx.x - off] : 0;
        __syncthreads();
        s[threadIdx.x] += t;
        __syncthreads();
    }
    if (i < n) ex[i] = s[threadIdx.x] - v;   // exclusive within block
    if (threadIdx.x == 1023) blkSum[blockIdx.x] = s[1023];
}

__global__ void k_scan2(const int* __restrict__ blkSum, int nb, int* blkOff, int* totalOut) {
    __shared__ int s[128];
    int t = threadIdx.x;
    int v = (t < nb) ? blkSum[t] : 0;
    s[t] = v;
    __syncthreads();
    for (int off = 1; off < 128; off <<= 1) {
        int x = (t >= off) ? s[t - off] : 0;
        __syncthreads();
        s[t] += x;
        __syncthreads();
    }
    if (t < nb) blkOff[t] = s[t] - v;
    if (t == 127) *totalOut = s[127];  // row_ptr[N] = total edge count
}

__global__ void k_scan3(int* row_ptr, int* cursor, const int* __restrict__ blkOff, int n) {
    int i = blockIdx.x * blockDim.x + threadIdx.x;
    if (i < n) {
        int v = row_ptr[i] + blkOff[i >> 10];
        row_ptr[i] = v;
        cursor[i] = v;
    }
}

__global__ void k_scatter(const int* __restrict__ srcA, const int* __restrict__ dstA,
                          int e, int n, int* cursor, int* __restrict__ col) {
    int i = blockIdx.x * blockDim.x + threadIdx.x;
    if (i < e) {
        int d = dstA[i];
        int pos = atomicAdd(&cursor[d], 1);
        col[pos] = srcA[i];
    } else if (i < e + n) {
        int v = i - e;  // self loop
        int pos = atomicAdd(&cursor[v], 1);
        col[pos] = v;
    }
}

// ---------------- tiled GEMM + attention scores ----------------
// H = X @ W  (X:[n,K], W:[K,64]); ssrc = H.a_src, sdst = H.a_dst per row.
// 256 threads/block, 64x64 output tile, 4x4 register tile per thread.
template <int K>
__global__ __launch_bounds__(256) void k_gemm_att(
    const float* __restrict__ X, const float* __restrict__ W,
    const float* __restrict__ a_src, const float* __restrict__ a_dst,
    float* __restrict__ H, float* __restrict__ ssrc, float* __restrict__ sdst, int n) {
    constexpr int KP = K + 8;              // padded X row stride (floats)
    __shared__ float Xs[64 * KP];
    __shared__ float Ws[K * 68];           // padded W row stride = 68
    const int tid = threadIdx.x;
    const int row0 = blockIdx.x * 64;

    // stage W (K*64 floats) as float4s
    for (int i = tid; i < K * 16; i += 256) {
        int k = i >> 4, c4 = i & 15;
        float4 v = reinterpret_cast<const float4*>(W)[i];
        *reinterpret_cast<float4*>(&Ws[k * 68 + c4 * 4]) = v;
    }
    // stage X tile (64 rows x K floats) as float4s, zero-pad OOB rows
    constexpr int RQ = K / 4;              // float4s per row
    for (int i = tid; i < 64 * RQ; i += 256) {
        int r = i / RQ, c4 = i % RQ;
        float4 v = make_float4(0.f, 0.f, 0.f, 0.f);
        if (row0 + r < n) v = reinterpret_cast<const float4*>(X + (size_t)(row0 + r) * K)[c4];
        *reinterpret_cast<float4*>(&Xs[r * KP + c4 * 4]) = v;
    }
    __syncthreads();

    const int tx = tid & 15, ty = tid >> 4;   // 16x16 thread grid
    float acc[4][4] = {};
    for (int k = 0; k < K; k += 4) {
        float4 xv[4], wv[4];
#pragma unroll
        for (int r = 0; r < 4; ++r)
            xv[r] = *reinterpret_cast<const float4*>(&Xs[(ty * 4 + r) * KP + k]);
#pragma unroll
        for (int j = 0; j < 4; ++j)
            wv[j] = *reinterpret_cast<const float4*>(&Ws[(k + j) * 68 + tx * 4]);
#pragma unroll
        for (int r = 0; r < 4; ++r) {
            const float* xp = reinterpret_cast<const float*>(&xv[r]);
#pragma unroll
            for (int j = 0; j < 4; ++j) {
                const float* wp = reinterpret_cast<const float*>(&wv[j]);
#pragma unroll
                for (int c = 0; c < 4; ++c) acc[r][c] += xp[j] * wp[c];
            }
        }
    }

    // epilogue: store H, reduce attention scores across the 16 tx lanes
    float4 av = reinterpret_cast<const float4*>(a_src)[tx];
    float4 dv = reinterpret_cast<const float4*>(a_dst)[tx];
#pragma unroll
    for (int r = 0; r < 4; ++r) {
        int row = row0 + ty * 4 + r;
        if (row < n) {
            float4 o = make_float4(acc[r][0], acc[r][1], acc[r][2], acc[r][3]);
            reinterpret_cast<float4*>(H + (size_t)row * 64)[tx] = o;
            float ps = acc[r][0] * av.x + acc[r][1] * av.y + acc[r][2] * av.z + acc[r][3] * av.w;
            float pd = acc[r][0] * dv.x + acc[r][1] * dv.y + acc[r][2] * dv.z + acc[r][3] * dv.w;
#pragma unroll
            for (int off = 1; off < 16; off <<= 1) {
                ps += __shfl_xor(ps, off);
                pd += __shfl_xor(pd, off);
            }
            if (tx == 0) {
                ssrc[row] = ps;
                sdst[row] = pd;
            }
        }
    }
}

// ---------------- GAT aggregation (online softmax) ----------------
// one wave per dst node; lane = feature
__global__ __launch_bounds__(256) void k_agg(
    const float* __restrict__ H, const float* __restrict__ ssrc,
    const float* __restrict__ sdst, const int* __restrict__ row_ptr,
    const int* __restrict__ col, const float* __restrict__ bias,
    float* __restrict__ Y, int n) {
    int dst = blockIdx.x * 4 + (threadIdx.x >> 6);
    int lane = threadIdx.x & 63;
    if (dst >= n) return;
    int beg = row_ptr[dst], end = row_ptr[dst + 1];
    float sd = sdst[dst];
    float m = -INFINITY, denom = 0.f, acc = 0.f;
    for (int j = beg; j < end; ++j) {
        int src = col[j];
        float e = ssrc[src] + sd;
        e = (e > 0.f) ? e : 0.2f * e;  // LeakyReLU
        float hv = H[(size_t)src * 64 + lane];
        if (e > m) {                    // wave-uniform branch (e lane-invariant)
            float c = __expf(m - e);    // first iter: exp(-inf)=0
            denom = denom * c + 1.f;
            acc = acc * c + hv;
            m = e;
        } else {
            float w = __expf(e - m);
            denom += w;
            acc += w * hv;
        }
    }
    float o = acc / denom + bias[lane];
    Y[(size_t)dst * 64 + lane] = (o > 0.f) ? o : 0.f;
}

// ---------------- pooling boundaries + pool + FC ----------------
__global__ void k_gstart(const int* __restrict__ batch, int n, int* gs) {
    int g = blockIdx.x * blockDim.x + threadIdx.x;
    if (g > NG) return;
    int lo = 0, hi = n;
    while (lo < hi) {
        int mid = (lo + hi) >> 1;
        if (batch[mid] < g) lo = mid + 1; else hi = mid;
    }
    gs[g] = lo;
}

__global__ __launch_bounds__(64) void k_pool_fc(
    const float* __restrict__ Y, const int* __restrict__ gs,
    const float* __restrict__ fcW, const float* __restrict__ fcb,
    float* __restrict__ out) {
    __shared__ float p[64];
    int g = blockIdx.x, lane = threadIdx.x;
    int b = gs[g], e = gs[g + 1];
    float s = 0.f;
    for (int r = b; r < e; ++r) s += Y[(size_t)r * 64 + lane];
    int cnt = e - b;
    p[lane] = s / (float)(cnt > 0 ? cnt : 1);
    __syncthreads();
    if (lane < 32) {
        float acc = fcb[lane];
#pragma unroll
        for (int k = 0; k < 64; ++k) acc += p[k] * fcW[k * 32 + lane];
        out[g * 32 + lane] = acc;
    }
}

// ---------------- launch ----------------
extern "C" void kernel_launch(void* const* d_in, const int* in_sizes, int n_in,
                              void* d_out, int out_size, void* d_ws, size_t ws_size,
                              hipStream_t stream) {
    const float* x = (const float*)d_in[0];
    const int* ei = (const int*)d_in[1];
    const int* batch = (const int*)d_in[2];
    const float* W0 = (const float*)d_in[3];
    const float* as0 = (const float*)d_in[4];
    const float* ad0 = (const float*)d_in[5];
    const float* b0 = (const float*)d_in[6];
    const float* W1 = (const float*)d_in[7];
    const float* as1 = (const float*)d_in[8];
    const float* ad1 = (const float*)d_in[9];
    const float* b1 = (const float*)d_in[10];
    const float* W2 = (const float*)d_in[11];
    const float* as2 = (const float*)d_in[12];
    const float* ad2 = (const float*)d_in[13];
    const float* b2 = (const float*)d_in[14];
    const float* fcW = (const float*)d_in[15];
    const float* fcb = (const float*)d_in[16];
    float* out = (float*)d_out;

    char* w = (char*)d_ws;
    auto alloc = [&](size_t bytes) {
        void* p = (void*)w;
        w += (bytes + 255) & ~(size_t)255;
        return p;
    };
    int* cnt_cursor = (int*)alloc((size_t)NN * 4);       // counts, then cursor
    int* row_ptr = (int*)alloc((size_t)(NN + 1) * 4);
    int* blkSum = (int*)alloc(512);
    int* blkOff = (int*)alloc(512);
    int* col = (int*)alloc((size_t)(NE + NN) * 4);
    int* gs = (int*)alloc((size_t)(NG + 1) * 4);
    float* H = (float*)alloc((size_t)NN * 64 * 4);
    float* Y = (float*)alloc((size_t)NN * 64 * 4);
    float* ssrc = (float*)alloc((size_t)NN * 4);
    float* sdst = (float*)alloc((size_t)NN * 4);

    const int* srcA = ei;
    const int* dstA = ei + NE;

    // CSR build
    k_init_cnt<<<(NN + 255) / 256, 256, 0, stream>>>(cnt_cursor, NN);
    k_hist<<<(NE + 255) / 256, 256, 0, stream>>>(dstA, NE, cnt_cursor);
    const int nb = (NN + 1023) / 1024;  // 98
    k_scan1<<<nb, 1024, 0, stream>>>(cnt_cursor, NN, row_ptr, blkSum);
    k_scan2<<<1, 128, 0, stream>>>(blkSum, nb, blkOff, row_ptr + NN);
    k_scan3<<<(NN + 255) / 256, 256, 0, stream>>>(row_ptr, cnt_cursor, blkOff, NN);
    k_scatter<<<(NE + NN + 255) / 256, 256, 0, stream>>>(srcA, dstA, NE, NN, cnt_cursor, col);
    k_gstart<<<3, 256, 0, stream>>>(batch, NN, gs);

    const int gemm_grid = (NN + 63) / 64;   // 64-row tile per block
    const int agg_grid = (NN + 3) / 4;      // 4 waves per block, wave per dst

    // layer 0
    k_gemm_att<128><<<gemm_grid, 256, 0, stream>>>(x, W0, as0, ad0, H, ssrc, sdst, NN);
    k_agg<<<agg_grid, 256, 0, stream>>>(H, ssrc, sdst, row_ptr, col, b0, Y, NN);
    // layer 1
    k_gemm_att<64><<<gemm_grid, 256, 0, stream>>>(Y, W1, as1, ad1, H, ssrc, sdst, NN);
    k_agg<<<agg_grid, 256, 0, stream>>>(H, ssrc, sdst, row_ptr, col, b1, Y, NN);
    // layer 2
    k_gemm_att<64><<<gemm_grid, 256, 0, stream>>>(Y, W2, as2, ad2, H, ssrc, sdst, NN);
    k_agg<<<agg_grid, 256, 0, stream>>>(H, ssrc, sdst, row_ptr, col, b2, Y, NN);

    // pool + FC
    k_pool_fc<<<NG, 64, 0, stream>>>(Y, gs, fcW, fcb, out);
}

// Round 3
// 576.021 us; speedup vs baseline: 1.9519x; 1.2697x over previous
//
#include <hip/hip_runtime.h>
#include <hip/hip_bf16.h>

#define NN 100000
#define NE 1200000
#define NG 512

// ---------------- CSR build ----------------
__global__ void k_init_cnt(int* cnt, int n) {
    int i = blockIdx.x * blockDim.x + threadIdx.x;
    if (i < n) cnt[i] = 1;  // self-loop contributes 1 per node
}

__global__ void k_hist(const int* __restrict__ dst, int e, int* cnt) {
    int i = blockIdx.x * blockDim.x + threadIdx.x;
    if (i < e) atomicAdd(&cnt[dst[i]], 1);
}

__global__ void k_scan1(const int* __restrict__ cnt, int n, int* ex, int* blkSum) {
    __shared__ int s[1024];
    int i = blockIdx.x * 1024 + threadIdx.x;
    int v = (i < n) ? cnt[i] : 0;
    s[threadIdx.x] = v;
    __syncthreads();
    for (int off = 1; off < 1024; off <<= 1) {
        int t = (threadIdx.x >= off) ? s[threadIdx.x - off] : 0;
        __syncthreads();
        s[threadIdx.x] += t;
        __syncthreads();
    }
    if (i < n) ex[i] = s[threadIdx.x] - v;   // exclusive within block
    if (threadIdx.x == 1023) blkSum[blockIdx.x] = s[1023];
}

__global__ void k_scan2(const int* __restrict__ blkSum, int nb, int* blkOff, int* totalOut) {
    __shared__ int s[128];
    int t = threadIdx.x;
    int v = (t < nb) ? blkSum[t] : 0;
    s[t] = v;
    __syncthreads();
    for (int off = 1; off < 128; off <<= 1) {
        int x = (t >= off) ? s[t - off] : 0;
        __syncthreads();
        s[t] += x;
        __syncthreads();
    }
    if (t < nb) blkOff[t] = s[t] - v;
    if (t == 127) *totalOut = s[127];  // row_ptr[N] = total edge count
}

__global__ void k_scan3(int* row_ptr, int* cursor, const int* __restrict__ blkOff, int n) {
    int i = blockIdx.x * blockDim.x + threadIdx.x;
    if (i < n) {
        int v = row_ptr[i] + blkOff[i >> 10];
        row_ptr[i] = v;
        cursor[i] = v;
    }
}

__global__ void k_scatter(const int* __restrict__ srcA, const int* __restrict__ dstA,
                          int e, int n, int* cursor, int* __restrict__ col) {
    int i = blockIdx.x * blockDim.x + threadIdx.x;
    if (i < e) {
        int d = dstA[i];
        int pos = atomicAdd(&cursor[d], 1);
        col[pos] = srcA[i];
    } else if (i < e + n) {
        int v = i - e;  // self loop
        int pos = atomicAdd(&cursor[v], 1);
        col[pos] = v;
    }
}

// ---------------- tiled GEMM + attention scores ----------------
// H = X @ W  (X:[n,K], W:[K,64]); ssrc = H.a_src, sdst = H.a_dst per row.
// 256 threads/block, 64x64 output tile, 4x4 register tile per thread.
template <int K>
__global__ __launch_bounds__(256) void k_gemm_att(
    const float* __restrict__ X, const float* __restrict__ W,
    const float* __restrict__ a_src, const float* __restrict__ a_dst,
    float* __restrict__ H, float* __restrict__ ssrc, float* __restrict__ sdst, int n) {
    constexpr int KP = K + 8;              // padded X row stride (floats)
    __shared__ float Xs[64 * KP];
    __shared__ float Ws[K * 68];           // padded W row stride = 68
    const int tid = threadIdx.x;
    const int row0 = blockIdx.x * 64;

    // stage W (K*64 floats) as float4s
    for (int i = tid; i < K * 16; i += 256) {
        int k = i >> 4, c4 = i & 15;
        float4 v = reinterpret_cast<const float4*>(W)[i];
        *reinterpret_cast<float4*>(&Ws[k * 68 + c4 * 4]) = v;
    }
    // stage X tile (64 rows x K floats) as float4s, zero-pad OOB rows
    constexpr int RQ = K / 4;              // float4s per row
    for (int i = tid; i < 64 * RQ; i += 256) {
        int r = i / RQ, c4 = i % RQ;
        float4 v = make_float4(0.f, 0.f, 0.f, 0.f);
        if (row0 + r < n) v = reinterpret_cast<const float4*>(X + (size_t)(row0 + r) * K)[c4];
        *reinterpret_cast<float4*>(&Xs[r * KP + c4 * 4]) = v;
    }
    __syncthreads();

    const int tx = tid & 15, ty = tid >> 4;   // 16x16 thread grid
    float acc[4][4] = {};
    for (int k = 0; k < K; k += 4) {
        float4 xv[4], wv[4];
#pragma unroll
        for (int r = 0; r < 4; ++r)
            xv[r] = *reinterpret_cast<const float4*>(&Xs[(ty * 4 + r) * KP + k]);
#pragma unroll
        for (int j = 0; j < 4; ++j)
            wv[j] = *reinterpret_cast<const float4*>(&Ws[(k + j) * 68 + tx * 4]);
#pragma unroll
        for (int r = 0; r < 4; ++r) {
            const float* xp = reinterpret_cast<const float*>(&xv[r]);
#pragma unroll
            for (int j = 0; j < 4; ++j) {
                const float* wp = reinterpret_cast<const float*>(&wv[j]);
#pragma unroll
                for (int c = 0; c < 4; ++c) acc[r][c] += xp[j] * wp[c];
            }
        }
    }

    // epilogue: store H, reduce attention scores across the 16 tx lanes
    float4 av = reinterpret_cast<const float4*>(a_src)[tx];
    float4 dv = reinterpret_cast<const float4*>(a_dst)[tx];
#pragma unroll
    for (int r = 0; r < 4; ++r) {
        int row = row0 + ty * 4 + r;
        if (row < n) {
            float4 o = make_float4(acc[r][0], acc[r][1], acc[r][2], acc[r][3]);
            reinterpret_cast<float4*>(H + (size_t)row * 64)[tx] = o;
            float ps = acc[r][0] * av.x + acc[r][1] * av.y + acc[r][2] * av.z + acc[r][3] * av.w;
            float pd = acc[r][0] * dv.x + acc[r][1] * dv.y + acc[r][2] * dv.z + acc[r][3] * dv.w;
#pragma unroll
            for (int off = 1; off < 16; off <<= 1) {
                ps += __shfl_xor(ps, off);
                pd += __shfl_xor(pd, off);
            }
            if (tx == 0) {
                ssrc[row] = ps;
                sdst[row] = pd;
            }
        }
    }
}

// ---------------- attention softmax, phase 1 (scalar, thread per dst) ----------------
// wgt[j] <- exp(e_j - m_dst)  (unnormalized), denom[dst] <- sum_j wgt[j]
__global__ __launch_bounds__(256) void k_att(
    const float* __restrict__ ssrc, const float* __restrict__ sdst,
    const int* __restrict__ row_ptr, const int* __restrict__ col,
    float* __restrict__ wgt, float* __restrict__ denom, int n) {
    int d = blockIdx.x * blockDim.x + threadIdx.x;
    if (d >= n) return;
    int beg = row_ptr[d], end = row_ptr[d + 1];
    float sd = sdst[d];
    float m = -INFINITY;
    for (int j = beg; j < end; ++j) {
        float e = ssrc[col[j]] + sd;
        e = (e > 0.f) ? e : 0.2f * e;  // LeakyReLU
        wgt[j] = e;
        m = fmaxf(m, e);
    }
    float den = 0.f;
    for (int j = beg; j < end; ++j) {
        float w = __expf(wgt[j] - m);
        wgt[j] = w;
        den += w;
    }
    denom[d] = den;
}

// ---------------- attention aggregation, phase 2 (wave per dst, lane=feature) ----------------
__global__ __launch_bounds__(256) void k_agg2(
    const float* __restrict__ H, const float* __restrict__ wgt,
    const float* __restrict__ denom, const int* __restrict__ row_ptr,
    const int* __restrict__ col, const float* __restrict__ bias,
    float* __restrict__ Y, int n) {
    int dst = blockIdx.x * 4 + (threadIdx.x >> 6);
    int lane = threadIdx.x & 63;
    if (dst >= n) return;
    int beg = row_ptr[dst], end = row_ptr[dst + 1];
    float acc = 0.f;
    int j = beg;
    for (; j + 4 <= end; j += 4) {
        int s0 = col[j], s1 = col[j + 1], s2 = col[j + 2], s3 = col[j + 3];
        float w0 = wgt[j], w1 = wgt[j + 1], w2 = wgt[j + 2], w3 = wgt[j + 3];
        float h0 = H[(size_t)s0 * 64 + lane];
        float h1 = H[(size_t)s1 * 64 + lane];
        float h2 = H[(size_t)s2 * 64 + lane];
        float h3 = H[(size_t)s3 * 64 + lane];
        acc += w0 * h0;
        acc += w1 * h1;
        acc += w2 * h2;
        acc += w3 * h3;
    }
    for (; j < end; ++j) acc += wgt[j] * H[(size_t)col[j] * 64 + lane];
    float o = acc / denom[dst] + bias[lane];
    Y[(size_t)dst * 64 + lane] = fmaxf(o, 0.f);
}

// ---------------- pooling boundaries + pool + FC ----------------
__global__ void k_gstart(const int* __restrict__ batch, int n, int* gs) {
    int g = blockIdx.x * blockDim.x + threadIdx.x;
    if (g > NG) return;
    int lo = 0, hi = n;
    while (lo < hi) {
        int mid = (lo + hi) >> 1;
        if (batch[mid] < g) lo = mid + 1; else hi = mid;
    }
    gs[g] = lo;
}

__global__ __launch_bounds__(64) void k_pool_fc(
    const float* __restrict__ Y, const int* __restrict__ gs,
    const float* __restrict__ fcW, const float* __restrict__ fcb,
    float* __restrict__ out) {
    __shared__ float p[64];
    int g = blockIdx.x, lane = threadIdx.x;
    int b = gs[g], e = gs[g + 1];
    float s = 0.f;
    for (int r = b; r < e; ++r) s += Y[(size_t)r * 64 + lane];
    int cnt = e - b;
    p[lane] = s / (float)(cnt > 0 ? cnt : 1);
    __syncthreads();
    if (lane < 32) {
        float acc = fcb[lane];
#pragma unroll
        for (int k = 0; k < 64; ++k) acc += p[k] * fcW[k * 32 + lane];
        out[g * 32 + lane] = acc;
    }
}

// ---------------- launch ----------------
extern "C" void kernel_launch(void* const* d_in, const int* in_sizes, int n_in,
                              void* d_out, int out_size, void* d_ws, size_t ws_size,
                              hipStream_t stream) {
    const float* x = (const float*)d_in[0];
    const int* ei = (const int*)d_in[1];
    const int* batch = (const int*)d_in[2];
    const float* W0 = (const float*)d_in[3];
    const float* as0 = (const float*)d_in[4];
    const float* ad0 = (const float*)d_in[5];
    const float* b0 = (const float*)d_in[6];
    const float* W1 = (const float*)d_in[7];
    const float* as1 = (const float*)d_in[8];
    const float* ad1 = (const float*)d_in[9];
    const float* b1 = (const float*)d_in[10];
    const float* W2 = (const float*)d_in[11];
    const float* as2 = (const float*)d_in[12];
    const float* ad2 = (const float*)d_in[13];
    const float* b2 = (const float*)d_in[14];
    const float* fcW = (const float*)d_in[15];
    const float* fcb = (const float*)d_in[16];
    float* out = (float*)d_out;

    char* w = (char*)d_ws;
    auto alloc = [&](size_t bytes) {
        void* p = (void*)w;
        w += (bytes + 255) & ~(size_t)255;
        return p;
    };
    int* cnt_cursor = (int*)alloc((size_t)NN * 4);       // counts, then cursor
    int* row_ptr = (int*)alloc((size_t)(NN + 1) * 4);
    int* blkSum = (int*)alloc(512);
    int* blkOff = (int*)alloc(512);
    int* col = (int*)alloc((size_t)(NE + NN) * 4);
    int* gs = (int*)alloc((size_t)(NG + 1) * 4);
    float* H = (float*)alloc((size_t)NN * 64 * 4);
    float* Y = (float*)alloc((size_t)NN * 64 * 4);
    float* ssrc = (float*)alloc((size_t)NN * 4);
    float* sdst = (float*)alloc((size_t)NN * 4);
    float* wgt = (float*)alloc((size_t)(NE + NN) * 4);
    float* denom = (float*)alloc((size_t)NN * 4);

    const int* srcA = ei;
    const int* dstA = ei + NE;

    // CSR build
    k_init_cnt<<<(NN + 255) / 256, 256, 0, stream>>>(cnt_cursor, NN);
    k_hist<<<(NE + 255) / 256, 256, 0, stream>>>(dstA, NE, cnt_cursor);
    const int nb = (NN + 1023) / 1024;  // 98
    k_scan1<<<nb, 1024, 0, stream>>>(cnt_cursor, NN, row_ptr, blkSum);
    k_scan2<<<1, 128, 0, stream>>>(blkSum, nb, blkOff, row_ptr + NN);
    k_scan3<<<(NN + 255) / 256, 256, 0, stream>>>(row_ptr, cnt_cursor, blkOff, NN);
    k_scatter<<<(NE + NN + 255) / 256, 256, 0, stream>>>(srcA, dstA, NE, NN, cnt_cursor, col);
    k_gstart<<<3, 256, 0, stream>>>(batch, NN, gs);

    const int gemm_grid = (NN + 63) / 64;   // 64-row tile per block
    const int agg_grid = (NN + 3) / 4;      // 4 waves per block, wave per dst
    const int att_grid = (NN + 255) / 256;  // thread per dst

    // layer 0
    k_gemm_att<128><<<gemm_grid, 256, 0, stream>>>(x, W0, as0, ad0, H, ssrc, sdst, NN);
    k_att<<<att_grid, 256, 0, stream>>>(ssrc, sdst, row_ptr, col, wgt, denom, NN);
    k_agg2<<<agg_grid, 256, 0, stream>>>(H, wgt, denom, row_ptr, col, b0, Y, NN);
    // layer 1
    k_gemm_att<64><<<gemm_grid, 256, 0, stream>>>(Y, W1, as1, ad1, H, ssrc, sdst, NN);
    k_att<<<att_grid, 256, 0, stream>>>(ssrc, sdst, row_ptr, col, wgt, denom, NN);
    k_agg2<<<agg_grid, 256, 0, stream>>>(H, wgt, denom, row_ptr, col, b1, Y, NN);
    // layer 2
    k_gemm_att<64><<<gemm_grid, 256, 0, stream>>>(Y, W2, as2, ad2, H, ssrc, sdst, NN);
    k_att<<<att_grid, 256, 0, stream>>>(ssrc, sdst, row_ptr, col, wgt, denom, NN);
    k_agg2<<<agg_grid, 256, 0, stream>>>(H, wgt, denom, row_ptr, col, b2, Y, NN);

    // pool + FC
    k_pool_fc<<<NG, 64, 0, stream>>>(Y, gs, fcW, fcb, out);
}